// Round 6
// baseline (88.479 us; speedup 1.0000x reference)
//
#include <hip/hip_runtime.h>
#include <stdint.h>

// UnfoldConv1d: y[b,o,t] = bias[o] + sum_j sum_c W[o, j*512+c] * x[b,c,t-2+j]
// bf16 MFMA GEMM, 256x256 tile, BK=64, 8 waves (2Mx4N).
// v6: faithful m201-template port. Per phase: {in-phase ds_reads (12/4/8/4) |
// stage exactly 1 half-tile (2 gload_lds) | s_barrier | lgkmcnt(0) | setprio1 |
// 16 MFMA (one quadrant x K=64) | setprio0 | s_barrier}. ONE vmcnt(4) per
// K-tile (end of ph4). B-LDS rows permuted (nh*128+wn*32+r) so stage halves
// match read quadrants. Chunk-XOR swizzle on both sides (conflict-free,
// measured 0 in R2/R4).

typedef float    f32x4  __attribute__((ext_vector_type(4)));
typedef short    bf16x8 __attribute__((ext_vector_type(8)));

#define C_DIM   512
#define T_DIM   4096
#define TP_DIM  4104
#define OUT_DIM 512
#define KF_DIM  1536
#define B_DIM   8

__device__ __forceinline__ uint16_t f2bf(float f) {
  union { float f; uint32_t u; } v; v.f = f;
  uint32_t u = v.u;
  return (uint16_t)((u + 0x7fffu + ((u >> 16) & 1u)) >> 16);  // RNE
}

__device__ __forceinline__ void gload_lds16(const uint16_t* g, uint16_t* l) {
  __builtin_amdgcn_global_load_lds(
      (const __attribute__((address_space(1))) uint32_t*)g,
      (__attribute__((address_space(3))) uint32_t*)l, 16, 0, 0);
}

// Stage 64 A-rows (identity row map). a = W-tile row0 (wsrc + kt*64).
__device__ __forceinline__ void stage_a(const uint16_t* __restrict__ a,
                                        uint16_t* lds, int r0, int tid) {
  int row = r0 + (tid >> 3);
  const uint16_t* src = a + (long)row * KF_DIM + (((tid & 7) ^ (row & 7)) << 3);
  gload_lds16(src, lds + r0 * 64 + (tid >> 6) * 512);
}

// Stage 64 B-LDS rows with permuted source: LDS row L holds global n-row
// n = ((L>>5)&3)*64 + (L>>7)*32 + (L&31)  (i.e. LDS row = nh*128+wn*32+r).
__device__ __forceinline__ void stage_b(const uint16_t* __restrict__ bt,
                                        uint16_t* lds, int r0, int tid) {
  int L = r0 + (tid >> 3);
  int n = ((L >> 5) & 3) * 64 + (L >> 7) * 32 + (L & 31);
  const uint16_t* src = bt + (long)n * C_DIM + (((tid & 7) ^ (L & 7)) << 3);
  gload_lds16(src, lds + r0 * 64 + (tid >> 6) * 512);
}

#define BAR()   __builtin_amdgcn_s_barrier()
#define LGKM0() asm volatile("s_waitcnt lgkmcnt(0)" ::: "memory")
#define LGKM8() asm volatile("s_waitcnt lgkmcnt(8)" ::: "memory")
#define VM(n)   asm volatile("s_waitcnt vmcnt(" #n ")" ::: "memory")
#define PRIO1() __builtin_amdgcn_s_setprio(1)
#define PRIO0() __builtin_amdgcn_s_setprio(0)

#define READ_A(BUF, MH) do { \
  _Pragma("unroll") for (int mi = 0; mi < 4; ++mi) { \
    const int row_ = wm * 128 + (MH) * 64 + mi * 16 + lr; \
    _Pragma("unroll") for (int kk = 0; kk < 2; ++kk) \
      af[mi][kk] = *(const bf16x8*)&(BUF)[row_ * 64 + (((kk * 4 + g) ^ (lr & 7)) << 3)]; \
  } } while (0)

#define READ_B(BUF, NH) do { \
  _Pragma("unroll") for (int ni = 0; ni < 2; ++ni) { \
    const int row_ = (NH) * 128 + wn * 32 + ni * 16 + lr; \
    _Pragma("unroll") for (int kk = 0; kk < 2; ++kk) \
      bfrag[ni][kk] = *(const bf16x8*)&(BUF)[row_ * 64 + (((kk * 4 + g) ^ (lr & 7)) << 3)]; \
  } } while (0)

#define MFMA16(MH, NH) do { PRIO1(); \
  _Pragma("unroll") for (int mi = 0; mi < 4; ++mi) \
  _Pragma("unroll") for (int ni = 0; ni < 2; ++ni) \
  _Pragma("unroll") for (int kk = 0; kk < 2; ++kk) \
    acc[(MH) * 4 + mi][(NH) * 2 + ni] = __builtin_amdgcn_mfma_f32_16x16x32_bf16( \
        af[mi][kk], bfrag[ni][kk], acc[(MH) * 4 + mi][(NH) * 2 + ni], 0, 0, 0); \
  PRIO0(); } while (0)

__device__ __forceinline__ const uint16_t* btile(const uint16_t* xsrc, int kb) {
  return xsrc + (kb >> 3) * C_DIM + ((kb & 7) << 6);
}

// One K-tile, 4 phases. MODE: 0 steady, 1 = kt==22 (stage kt+1 only, vm0),
// 2 = kt==23 (no stages/waits).
// Stage plan: ph1 -> (kt+1).B0 [oth], ph2 -> (kt+1).A1 [oth],
//             ph3 -> (kt+2).A0 [cur], ph4 -> (kt+2).B1 [cur], then VM(4).
template<int MODE>
__device__ __forceinline__ void ktile(
    f32x4 (&acc)[8][4], bf16x8 (&af)[4][2], bf16x8 (&bfrag)[2][2],
    uint16_t* cA, uint16_t* cB, uint16_t* oA, uint16_t* oB,
    const uint16_t* __restrict__ wsrc, const uint16_t* __restrict__ xsrc,
    int kt, int tid, int wm, int wn, int lr, int g) {
  const uint16_t* aN1 = wsrc + (kt + 1) * 64;
  const uint16_t* bN1 = btile(xsrc, kt + 1);
  const uint16_t* aN2 = wsrc + (kt + 2) * 64;
  const uint16_t* bN2 = btile(xsrc, kt + 2);

  // ph1: quadrant (0,0); 12 reads; stage (kt+1).B0
  READ_A(cA, 0); READ_B(cB, 0);
  if (MODE <= 1) { stage_b(bN1, oB, 0, tid); stage_b(bN1, oB, 64, tid); }
  LGKM8();
  BAR(); LGKM0(); MFMA16(0, 0); BAR();
  // ph2: quadrant (0,1); 4 reads; stage (kt+1).A1
  READ_B(cB, 1);
  if (MODE <= 1) { stage_a(aN1, oA, 128, tid); stage_a(aN1, oA, 192, tid); }
  BAR(); LGKM0(); MFMA16(0, 1); BAR();
  // ph3: quadrant (1,1); 8 reads; stage (kt+2).A0
  READ_A(cA, 1);
  if (MODE == 0) { stage_a(aN2, cA, 0, tid); stage_a(aN2, cA, 64, tid); }
  BAR(); LGKM0(); MFMA16(1, 1); BAR();
  // ph4: quadrant (1,0); 4 reads; stage (kt+2).B1; single counted vmcnt
  READ_B(cB, 0);
  if (MODE == 0) { stage_b(bN2, cB, 128, tid); stage_b(bN2, cB, 192, tid); }
  BAR(); LGKM0(); MFMA16(1, 0);
  if (MODE == 0) { VM(4); }
  else if (MODE == 1) { VM(0); }
  BAR();
}

// grid (T/256=16, OUT/256=2, B=8), 512 threads = 8 waves (2M x 4N).
__global__ __launch_bounds__(512, 2) void gemm_kernel(
    const uint16_t* __restrict__ xp, const uint16_t* __restrict__ Wb,
    const float* __restrict__ bias, float* __restrict__ out) {
  __shared__ __align__(16) uint16_t LA0[256 * 64];
  __shared__ __align__(16) uint16_t LB0[256 * 64];
  __shared__ __align__(16) uint16_t LA1[256 * 64];
  __shared__ __align__(16) uint16_t LB1[256 * 64];

  const int tid  = threadIdx.x;
  const int lane = tid & 63;
  const int wid  = tid >> 6;
  const int wm   = wid >> 2;     // 0..1  (o / A side, 128 rows)
  const int wn   = wid & 3;      // 0..3  (t / B side, 64 rows)
  const int lr   = lane & 15;
  const int g    = lane >> 4;
  const int t0 = blockIdx.x * 256;
  const int o0 = blockIdx.y * 256;
  const int b  = blockIdx.z;

  const uint16_t* wsrc = Wb + (long)o0 * KF_DIM;
  const uint16_t* xsrc = xp + ((long)b * TP_DIM + t0) * C_DIM;

  f32x4 acc[8][4];
  #pragma unroll
  for (int mi = 0; mi < 8; ++mi)
    #pragma unroll
    for (int ni = 0; ni < 4; ++ni)
      #pragma unroll
      for (int r = 0; r < 4; ++r) acc[mi][ni][r] = 0.0f;

  bf16x8 af[4][2], bfrag[2][2];

  // ---- prologue: tile0 all 4 halves, then tile1 {A0, B1}; VM(4) leaves
  // exactly tile1's 2 half-tiles (4 loads) in flight = steady-state shape.
  {
    const uint16_t* a1 = wsrc + 64;
    const uint16_t* b1 = btile(xsrc, 1);
    stage_a(wsrc, LA0, 0, tid);   stage_a(wsrc, LA0, 64, tid);    // t0.A0
    stage_a(wsrc, LA0, 128, tid); stage_a(wsrc, LA0, 192, tid);   // t0.A1
    stage_b(xsrc, LB0, 0, tid);   stage_b(xsrc, LB0, 64, tid);    // t0.B0
    stage_b(xsrc, LB0, 128, tid); stage_b(xsrc, LB0, 192, tid);   // t0.B1
    stage_a(a1, LA1, 0, tid);     stage_a(a1, LA1, 64, tid);      // t1.A0
    stage_b(b1, LB1, 128, tid);   stage_b(b1, LB1, 192, tid);     // t1.B1
    VM(4);
    BAR();
  }

  // ---- main loop: 24 K-tiles = 11 steady pairs + kt=22 (MODE1) + 23 (MODE2)
  #pragma unroll 1
  for (int i = 0; i < 11; ++i) {
    ktile<0>(acc, af, bfrag, LA0, LB0, LA1, LB1, wsrc, xsrc, 2 * i,     tid, wm, wn, lr, g);
    ktile<0>(acc, af, bfrag, LA1, LB1, LA0, LB0, wsrc, xsrc, 2 * i + 1, tid, wm, wn, lr, g);
  }
  ktile<1>(acc, af, bfrag, LA0, LB0, LA1, LB1, wsrc, xsrc, 22, tid, wm, wn, lr, g);
  ktile<2>(acc, af, bfrag, LA1, LB1, LA0, LB0, wsrc, xsrc, 23, tid, wm, wn, lr, g);

  // ---- epilogue: D col=lane&15 (t), row=(lane>>4)*4+r (o) ----
  // acc col nidx -> n = wn*64 + (nidx>>1)*32 + (nidx&1)*16 + lr == wn*64+nidx*16+lr
  #pragma unroll
  for (int mi = 0; mi < 8; ++mi) {
    int orow = o0 + wm * 128 + mi * 16 + (lane >> 4) * 4;
    #pragma unroll
    for (int ni = 0; ni < 4; ++ni) {
      int t = t0 + wn * 64 + ni * 16 + lr;
      float* op = out + ((long)b * OUT_DIM + orow) * T_DIM + t;
      #pragma unroll
      for (int r = 0; r < 4; ++r)
        op[(long)r * T_DIM] = acc[mi][ni][r] + bias[orow + r];
    }
  }
}

// ---------------- prep: W fp32 [512][1536] -> bf16 same layout ----------------
__global__ __launch_bounds__(256) void prep_w(const float* __restrict__ W,
                                              uint16_t* __restrict__ Wb) {
  int i = blockIdx.x * 256 + threadIdx.x;
  if (i >= 196608) return;
  float4 v = ((const float4*)W)[i];
  ushort4 o;
  o.x = f2bf(v.x); o.y = f2bf(v.y); o.z = f2bf(v.z); o.w = f2bf(v.w);
  ((ushort4*)Wb)[i] = o;
}

// ------ prep: x fp32 [b][c][t] -> xp bf16 [b][tp][c], tp=t+2, TP=4104 --------
__global__ __launch_bounds__(256) void prep_x(const float* __restrict__ x,
                                              uint16_t* __restrict__ xp) {
  __shared__ uint16_t tile[128 * 65];  // [c 128][t 64], stride 65
  const int tid = threadIdx.x;
  const int tp0 = blockIdx.x * 64;
  const int c0  = blockIdx.y * 128;
  const int b   = blockIdx.z;

  const int p = tid & 31;
  const int t = tp0 - 2 + p * 2;
  const bool ok = (t >= 0) && (t < T_DIM);
  #pragma unroll
  for (int it = 0; it < 16; ++it) {
    int cr = it * 8 + (tid >> 5);
    float vx = 0.f, vy = 0.f;
    if (ok) {
      const float2 v = *(const float2*)(x + (long)(b * C_DIM + c0 + cr) * T_DIM + t);
      vx = v.x; vy = v.y;
    }
    tile[cr * 65 + 2 * p]     = f2bf(vx);
    tile[cr * 65 + 2 * p + 1] = f2bf(vy);
  }
  __syncthreads();

  const int q = tid & 31;
  #pragma unroll
  for (int it = 0; it < 8; ++it) {
    int r = it * 8 + (tid >> 5);
    int tp = tp0 + r;
    if (tp < TP_DIM) {
      ushort4 val;
      val.x = tile[(4 * q + 0) * 65 + r];
      val.y = tile[(4 * q + 1) * 65 + r];
      val.z = tile[(4 * q + 2) * 65 + r];
      val.w = tile[(4 * q + 3) * 65 + r];
      *(ushort4*)(xp + (long)(b * TP_DIM + tp) * C_DIM + c0 + 4 * q) = val;
    }
  }
}

// ------------------------- naive fallback (no ws) ----------------------------
__global__ __launch_bounds__(256) void naive_kernel(const float* __restrict__ x,
                                                    const float* __restrict__ W,
                                                    const float* __restrict__ bias,
                                                    float* __restrict__ y) {
  int t = blockIdx.x * 256 + threadIdx.x;
  int o = blockIdx.y, b = blockIdx.z;
  float s = bias[o];
  #pragma unroll
  for (int j = 0; j < 3; ++j) {
    int tt = t - 2 + j;
    if (tt < 0) continue;
    const float* xr = x + (long)b * C_DIM * T_DIM + tt;
    const float* wr = W + (long)o * KF_DIM + j * C_DIM;
    float a = 0.f;
    for (int c = 0; c < C_DIM; ++c) a += wr[c] * xr[(long)c * T_DIM];
    s += a;
  }
  y[((long)b * OUT_DIM + o) * T_DIM + t] = s;
}

extern "C" void kernel_launch(void* const* d_in, const int* in_sizes, int n_in,
                              void* d_out, int out_size, void* d_ws, size_t ws_size,
                              hipStream_t stream) {
  (void)in_sizes; (void)n_in; (void)out_size;
  const float* x    = (const float*)d_in[0];
  const float* W    = (const float*)d_in[1];
  const float* bias = (const float*)d_in[2];
  float* out = (float*)d_out;

  const size_t wb_elems = (size_t)OUT_DIM * KF_DIM;          // 786432
  const size_t xp_elems = (size_t)B_DIM * TP_DIM * C_DIM;    // 16809984
  const size_t need = (wb_elems + xp_elems) * sizeof(uint16_t);

  if (ws_size < need) {  // insurance: slow but correct
    naive_kernel<<<dim3(T_DIM / 256, OUT_DIM, B_DIM), 256, 0, stream>>>(x, W, bias, out);
    return;
  }

  uint16_t* Wb = (uint16_t*)d_ws;
  uint16_t* xp = (uint16_t*)d_ws + wb_elems;

  prep_w<<<768, 256, 0, stream>>>(W, Wb);
  prep_x<<<dim3(65, 4, 8), 256, 0, stream>>>(x, xp);
  gemm_kernel<<<dim3(16, 2, 8), 512, 0, stream>>>(xp, Wb, bias, out);
}